// Round 1
// baseline (2636.819 us; speedup 1.0000x reference)
//
#include <hip/hip_runtime.h>
#include <cstddef>

#define NB 32
#define NC 4
#define NH 512
#define NW 512
#define PLANE (NH * NW)
#define NSTEPS 8

// Block-wide (256-thread) sum reduction. Valid result only in threadIdx.x==0.
__device__ __forceinline__ float blockReduce256(float v, float* sm) {
#pragma unroll
    for (int off = 32; off > 0; off >>= 1) v += __shfl_down(v, off, 64);
    int lane = threadIdx.x & 63;
    int wave = threadIdx.x >> 6;
    if (lane == 0) sm[wave] = v;
    __syncthreads();
    return (threadIdx.x == 0) ? ((sm[0] + sm[1]) + (sm[2] + sm[3])) : 0.0f;
}

// Computes per-(batch,channel) sums of the input and copies channels 1..3 to out.
// grid.x = NB*NC*16 (16 chunks per 512x512 plane), block = 256.
__global__ void mean_copy_kernel(const float* __restrict__ x,
                                 float* __restrict__ out,
                                 float* __restrict__ sumsAll) {
    int id = blockIdx.x;
    int chunk = id & 15;
    int c = (id >> 4) & 3;
    int b = id >> 6;
    size_t base = (size_t)(b * NC + c) * PLANE + (size_t)chunk * (PLANE / 16);
    const float4* s4 = (const float4*)(x + base);
    float4* d4 = (float4*)(out + base);
    float s = 0.0f;
    const int nvec = (PLANE / 16) / 4;  // 4096 float4 per chunk
    for (int j = threadIdx.x; j < nvec; j += 256) {
        float4 v = s4[j];
        s += (v.x + v.y) + (v.z + v.w);
        if (c != 0) d4[j] = v;
    }
    __shared__ float sm[4];
    float tot = blockReduce256(s, sm);
    if (threadIdx.x == 0) atomicAdd(&sumsAll[b * NC + c], tot);
}

// One reaction-diffusion step on channel 0 of every batch.
// grid = (NW/256, NH, NB), block = 256. Fuses:
//  - per-block param computation (sigmoid of feats @ W + b, mask folded into D,rho)
//  - the stencil update
//  - accumulation of the NEW field's per-batch sum (for the next step's params)
__global__ void step_kernel(const float* __restrict__ src, int srcStride,
                            float* __restrict__ dst, int dstStride,
                            const float* __restrict__ sumsAll,
                            const float* __restrict__ ch0sum, int ch0Stride,
                            const float* __restrict__ Wm, const float* __restrict__ bv,
                            const int* __restrict__ t, int stepIdx,
                            float* __restrict__ nextSum, int writeSum) {
    __shared__ float prm[2];
    __shared__ float sm[4];
    int b = blockIdx.z;
    if (threadIdx.x == 0) {
        const float inv = 1.0f / (float)PLANE;
        float f0 = ch0sum[b * ch0Stride] * inv;
        float f1 = sumsAll[b * NC + 1] * inv;
        float f2 = sumsAll[b * NC + 2] * inv;
        float f3 = sumsAll[b * NC + 3] * inv;
        float z0 = f0 * Wm[0] + f1 * Wm[2] + f2 * Wm[4] + f3 * Wm[6] + bv[0];
        float z1 = f0 * Wm[1] + f1 * Wm[3] + f2 * Wm[5] + f3 * Wm[7] + bv[1];
        bool m = t[b] > stepIdx;
        prm[0] = m ? 0.2f / (1.0f + expf(-z0)) : 0.0f;  // D (mask folded)
        prm[1] = m ? 0.1f / (1.0f + expf(-z1)) : 0.0f;  // rho (mask folded)
    }
    __syncthreads();
    float D = prm[0];
    float rho = prm[1];

    const float* sp = src + (size_t)b * srcStride;
    float* dp = dst + (size_t)b * dstStride;
    int x = blockIdx.x * 256 + threadIdx.x;
    int y = blockIdx.y;
    int xl = (x - 1) & (NW - 1);
    int xr = (x + 1) & (NW - 1);
    int yu = (y - 1) & (NH - 1);
    int yd = (y + 1) & (NH - 1);
    float u = sp[y * NW + x];
    float lap = sp[yu * NW + x] + sp[yd * NW + x] + sp[y * NW + xl] +
                sp[y * NW + xr] - 4.0f * u;
    float un = u + (D * lap + rho * u * (1.0f - u));
    dp[y * NW + x] = un;

    if (writeSum) {
        float tot = blockReduce256(un, sm);
        if (threadIdx.x == 0) atomicAdd(&nextSum[b], tot);
    }
}

extern "C" void kernel_launch(void* const* d_in, const int* in_sizes, int n_in,
                              void* d_out, int out_size, void* d_ws, size_t ws_size,
                              hipStream_t stream) {
    const float* x = (const float*)d_in[0];
    const float* Wm = (const float*)d_in[1];
    const float* bv = (const float*)d_in[2];
    const int* t = (const int*)d_in[3];
    float* out = (float*)d_out;

    // ws layout: [u ping-pong buffer: NB*PLANE floats][sumsAll: NB*NC][stepSums: (NSTEPS+1)*NB]
    float* wsU = (float*)d_ws;
    float* sumsAll = wsU + (size_t)NB * PLANE;
    float* stepSums = sumsAll + NB * NC;

    // Zero the sum accumulators (ws is poisoned to 0xAA before every call).
    hipMemsetAsync(sumsAll, 0, sizeof(float) * (NB * NC + (NSTEPS + 1) * NB), stream);

    // Channel sums + copy channels 1..3 to output.
    mean_copy_kernel<<<NB * NC * 16, 256, 0, stream>>>(x, out, sumsAll);

    for (int i = 0; i < NSTEPS; ++i) {
        const float* src;
        int srcStride;
        float* dst;
        int dstStride;
        if (i == 0) { src = x; srcStride = NC * PLANE; }
        else if (i & 1) { src = wsU; srcStride = PLANE; }
        else { src = out; srcStride = NC * PLANE; }
        if (i & 1) { dst = out; dstStride = NC * PLANE; }  // odd steps -> out ch0
        else { dst = wsU; dstStride = PLANE; }             // even steps -> ws
        const float* ch0 = (i == 0) ? sumsAll : (stepSums + (size_t)i * NB);
        int ch0Stride = (i == 0) ? NC : 1;

        dim3 grid(NW / 256, NH, NB);
        step_kernel<<<grid, 256, 0, stream>>>(
            src, srcStride, dst, dstStride, sumsAll, ch0, ch0Stride, Wm, bv, t, i,
            stepSums + (size_t)(i + 1) * NB, (i < NSTEPS - 1) ? 1 : 0);
    }
}

// Round 2
// 418.270 us; speedup vs baseline: 6.3041x; 6.3041x over previous
//
#include <hip/hip_runtime.h>
#include <cstddef>

#define NB 32
#define NC 4
#define NH 512
#define NW 512
#define PLANE (NH * NW)
#define NSTEPS 8
#define NSTRIPS 32
#define STRIP_ROWS (NH / NSTRIPS)  // 16 rows per block

// Block-wide (256-thread) sum reduction. Valid result only in threadIdx.x==0.
__device__ __forceinline__ float blockReduce256(float v, float* sm) {
#pragma unroll
    for (int off = 32; off > 0; off >>= 1) v += __shfl_down(v, off, 64);
    int lane = threadIdx.x & 63;
    int wave = threadIdx.x >> 6;
    if (lane == 0) sm[wave] = v;
    __syncthreads();
    return (threadIdx.x == 0) ? ((sm[0] + sm[1]) + (sm[2] + sm[3])) : 0.0f;
}

// Computes per-(batch,channel) sums of the input and copies channels 1..3 to out.
// grid.x = NB*NC*16 (16 chunks per 512x512 plane), block = 256.
__global__ void mean_copy_kernel(const float* __restrict__ x,
                                 float* __restrict__ out,
                                 float* __restrict__ sumsAll) {
    int id = blockIdx.x;
    int chunk = id & 15;
    int c = (id >> 4) & 3;
    int b = id >> 6;
    size_t base = (size_t)(b * NC + c) * PLANE + (size_t)chunk * (PLANE / 16);
    const float4* s4 = (const float4*)(x + base);
    float4* d4 = (float4*)(out + base);
    float s = 0.0f;
    const int nvec = (PLANE / 16) / 4;  // 4096 float4 per chunk
    for (int j = threadIdx.x; j < nvec; j += 256) {
        float4 v = s4[j];
        s += (v.x + v.y) + (v.z + v.w);
        if (c != 0) d4[j] = v;
    }
    __shared__ float sm[4];
    float tot = blockReduce256(s, sm);
    if (threadIdx.x == 0) atomicAdd(&sumsAll[b * NC + c], tot);
}

// One reaction-diffusion step on channel 0 of every batch.
// grid = (NSTRIPS, NB), block = 256. Each block handles a 16-row x 512-col
// strip: 64 elements per thread via float4, amortizing the per-block param
// load + barrier + reduction + atomic 64x vs the 1-elem/thread version.
__global__ void step_kernel(const float* __restrict__ src, int srcStride,
                            float* __restrict__ dst, int dstStride,
                            const float* __restrict__ sumsAll,
                            const float* __restrict__ ch0sum, int ch0Stride,
                            const float* __restrict__ Wm, const float* __restrict__ bv,
                            const int* __restrict__ t, int stepIdx,
                            float* __restrict__ nextSum, int writeSum) {
    __shared__ float prm[2];
    __shared__ float sm[4];
    int b = blockIdx.y;
    if (threadIdx.x == 0) {
        const float inv = 1.0f / (float)PLANE;
        float f0 = ch0sum[b * ch0Stride] * inv;
        float f1 = sumsAll[b * NC + 1] * inv;
        float f2 = sumsAll[b * NC + 2] * inv;
        float f3 = sumsAll[b * NC + 3] * inv;
        float z0 = f0 * Wm[0] + f1 * Wm[2] + f2 * Wm[4] + f3 * Wm[6] + bv[0];
        float z1 = f0 * Wm[1] + f1 * Wm[3] + f2 * Wm[5] + f3 * Wm[7] + bv[1];
        bool m = t[b] > stepIdx;
        prm[0] = m ? 0.2f / (1.0f + expf(-z0)) : 0.0f;  // D (mask folded)
        prm[1] = m ? 0.1f / (1.0f + expf(-z1)) : 0.0f;  // rho (mask folded)
    }
    __syncthreads();
    float D = prm[0];
    float rho = prm[1];

    const float* sp = src + (size_t)b * srcStride;
    float* dp = dst + (size_t)b * dstStride;

    int col4 = threadIdx.x & 127;   // float4 index within a row (512/4 = 128)
    int x0 = col4 * 4;
    int rowHalf = threadIdx.x >> 7; // 0 or 1
    int rowBase = blockIdx.x * STRIP_ROWS;

    float acc = 0.0f;
#pragma unroll 4
    for (int it = 0; it < STRIP_ROWS / 2; ++it) {
        int y = rowBase + it * 2 + rowHalf;
        int yu = (y - 1) & (NH - 1);
        int yd = (y + 1) & (NH - 1);
        float4 c = ((const float4*)(sp + (size_t)y * NW))[col4];
        float4 up = ((const float4*)(sp + (size_t)yu * NW))[col4];
        float4 dn = ((const float4*)(sp + (size_t)yd * NW))[col4];
        float lft = sp[(size_t)y * NW + ((x0 - 1) & (NW - 1))];
        float rgt = sp[(size_t)y * NW + ((x0 + 4) & (NW - 1))];
        float4 un;
        un.x = c.x + (D * (up.x + dn.x + lft + c.y - 4.0f * c.x) + rho * c.x * (1.0f - c.x));
        un.y = c.y + (D * (up.y + dn.y + c.x + c.z - 4.0f * c.y) + rho * c.y * (1.0f - c.y));
        un.z = c.z + (D * (up.z + dn.z + c.y + c.w - 4.0f * c.z) + rho * c.z * (1.0f - c.z));
        un.w = c.w + (D * (up.w + dn.w + c.z + rgt - 4.0f * c.w) + rho * c.w * (1.0f - c.w));
        ((float4*)(dp + (size_t)y * NW))[col4] = un;
        acc += (un.x + un.y) + (un.z + un.w);
    }

    if (writeSum) {
        float tot = blockReduce256(acc, sm);
        if (threadIdx.x == 0) atomicAdd(&nextSum[b], tot);
    }
}

extern "C" void kernel_launch(void* const* d_in, const int* in_sizes, int n_in,
                              void* d_out, int out_size, void* d_ws, size_t ws_size,
                              hipStream_t stream) {
    const float* x = (const float*)d_in[0];
    const float* Wm = (const float*)d_in[1];
    const float* bv = (const float*)d_in[2];
    const int* t = (const int*)d_in[3];
    float* out = (float*)d_out;

    // ws layout: [u ping-pong buffer: NB*PLANE floats][sumsAll: NB*NC][stepSums: (NSTEPS+1)*NB]
    float* wsU = (float*)d_ws;
    float* sumsAll = wsU + (size_t)NB * PLANE;
    float* stepSums = sumsAll + NB * NC;

    // Zero the sum accumulators (ws is poisoned to 0xAA before every call).
    hipMemsetAsync(sumsAll, 0, sizeof(float) * (NB * NC + (NSTEPS + 1) * NB), stream);

    // Channel sums + copy channels 1..3 to output.
    mean_copy_kernel<<<NB * NC * 16, 256, 0, stream>>>(x, out, sumsAll);

    for (int i = 0; i < NSTEPS; ++i) {
        const float* src;
        int srcStride;
        float* dst;
        int dstStride;
        if (i == 0) { src = x; srcStride = NC * PLANE; }
        else if (i & 1) { src = wsU; srcStride = PLANE; }
        else { src = out; srcStride = NC * PLANE; }
        if (i & 1) { dst = out; dstStride = NC * PLANE; }  // odd steps -> out ch0
        else { dst = wsU; dstStride = PLANE; }             // even steps -> ws
        const float* ch0 = (i == 0) ? sumsAll : (stepSums + (size_t)i * NB);
        int ch0Stride = (i == 0) ? NC : 1;

        dim3 grid(NSTRIPS, NB);
        step_kernel<<<grid, 256, 0, stream>>>(
            src, srcStride, dst, dstStride, sumsAll, ch0, ch0Stride, Wm, bv, t, i,
            stepSums + (size_t)(i + 1) * NB, (i < NSTEPS - 1) ? 1 : 0);
    }
}